// Round 5
// baseline (232.004 us; speedup 1.0000x reference)
//
#include <hip/hip_runtime.h>
#include <hip/hip_bf16.h>
#include <stdint.h>

typedef __attribute__((ext_vector_type(8))) short short8;
typedef __attribute__((ext_vector_type(4))) float f32x4;

// Problem constants
#define BATCH 4
#define SEQ   2048
#define EMB   1024
#define HEADS 16
#define DHEAD 64
#define MROWS (BATCH * SEQ)   // 8192

// exp(s/8) == exp2(s * 0.125*log2(e)); fold into Q at bf16-pack time
#define QSCALE 0.18033688011112042f

__device__ inline unsigned short f2bf(float f) {
    unsigned int u = __float_as_uint(f);
    unsigned int r = (u + 0x7fffu + ((u >> 16) & 1u)) >> 16;
    return (unsigned short)r;
}

__device__ __forceinline__ void gl_lds16(const short* g, short* l) {
    __builtin_amdgcn_global_load_lds(
        (const __attribute__((address_space(1))) void*)g,
        (__attribute__((address_space(3))) void*)l, 16, 0, 0);
}

// ---------------- fused pack x -> bf16 + f32 passthrough ----------------
__global__ __launch_bounds__(256) void pack_x(const float* __restrict__ src,
                                              unsigned short* __restrict__ dst,
                                              float* __restrict__ pass) {
    int i = (blockIdx.x * 256 + threadIdx.x) * 8;
    const float4* s = reinterpret_cast<const float4*>(src + i);
    float4 f0 = s[0];
    float4 f1 = s[1];
    union { unsigned short u[8]; short8 v; } o;
    o.u[0] = f2bf(f0.x); o.u[1] = f2bf(f0.y); o.u[2] = f2bf(f0.z); o.u[3] = f2bf(f0.w);
    o.u[4] = f2bf(f1.x); o.u[5] = f2bf(f1.y); o.u[6] = f2bf(f1.z); o.u[7] = f2bf(f1.w);
    *reinterpret_cast<short8*>(dst + i) = o.v;
    float4* p = reinterpret_cast<float4*>(pass + i);
    p[0] = f0;
    p[1] = f1;
}

// ---------------- pack 3 weights -> bf16, one dispatch ----------------
__global__ __launch_bounds__(256) void pack_w3(const float* __restrict__ wq,
                                               const float* __restrict__ wk,
                                               const float* __restrict__ wv,
                                               unsigned short* __restrict__ dq,
                                               unsigned short* __restrict__ dk,
                                               unsigned short* __restrict__ dv) {
    const float* src = blockIdx.y == 0 ? wq : blockIdx.y == 1 ? wk : wv;
    unsigned short* dst = blockIdx.y == 0 ? dq : blockIdx.y == 1 ? dk : dv;
    int i = (blockIdx.x * 256 + threadIdx.x) * 8;
    const float4* s = reinterpret_cast<const float4*>(src + i);
    float4 f0 = s[0];
    float4 f1 = s[1];
    union { unsigned short u[8]; short8 v; } o;
    o.u[0] = f2bf(f0.x); o.u[1] = f2bf(f0.y); o.u[2] = f2bf(f0.z); o.u[3] = f2bf(f0.w);
    o.u[4] = f2bf(f1.x); o.u[5] = f2bf(f1.y); o.u[6] = f2bf(f1.z); o.u[7] = f2bf(f1.w);
    *reinterpret_cast<short8*>(dst + i) = o.v;
}

// ---------------- GEMM (m97 structure): C[m,e] = sum_k A[m,k]*B[e,k] ----
// MODE 0: fused QK — grid.y spans 2048 cols = [Wq | Wk]; store bf16
//         head-major [2*64][SEQ][64] (Qh then Kh), Q scaled by QSCALE.
// MODE 1: V — store f32 to out, scaled by diag.
template <int MODE>
__global__ __launch_bounds__(256) void gemm_bt(const short* __restrict__ A,
                                               const short* __restrict__ Bm,
                                               unsigned short* __restrict__ Cb,
                                               float* __restrict__ out,
                                               const float* __restrict__ dgp) {
    constexpr int K = EMB;
    __shared__ short As[128 * 32];   // linear: global_load_lds needs lane-contiguous dest
    __shared__ short Bs[128 * 32];
    const int m0 = blockIdx.x * 128;
    const int n0 = blockIdx.y * 128;
    const int t = threadIdx.x;
    const int lane = t & 63;
    const int w = t >> 6;                // 4 waves
    const int wr = w >> 1, wc = w & 1;   // 2x2 wave grid, 64x64 per wave

    f32x4 acc[4][4] = {};

    const short* gA = A + (size_t)(m0 + (t >> 2)) * K + (t & 3) * 8;
    const short* gB = Bm + (size_t)(n0 + (t >> 2)) * K + (t & 3) * 8;
    short* lA0 = As + w * 512;           // wave-uniform LDS bases
    short* lA1 = As + 2048 + w * 512;
    short* lB0 = Bs + w * 512;
    short* lB1 = Bs + 2048 + w * 512;

    const int kq = (lane >> 4) * 8;
    const int fr = lane & 15;

    for (int k0 = 0; k0 < K; k0 += 32) {
        gl_lds16(gA + k0, lA0);
        gl_lds16(gA + 64 * K + k0, lA1);
        gl_lds16(gB + k0, lB0);
        gl_lds16(gB + 64 * K + k0, lB1);
        __syncthreads();

        short8 a[4], b[4];
#pragma unroll
        for (int i = 0; i < 4; i++)
            a[i] = *(const short8*)&As[(wr * 64 + i * 16 + fr) * 32 + kq];
#pragma unroll
        for (int j = 0; j < 4; j++)
            b[j] = *(const short8*)&Bs[(wc * 64 + j * 16 + fr) * 32 + kq];
#pragma unroll
        for (int i = 0; i < 4; i++)
#pragma unroll
            for (int j = 0; j < 4; j++)
                acc[i][j] = __builtin_amdgcn_mfma_f32_16x16x32_bf16(a[i], b[j], acc[i][j], 0, 0, 0);
        __syncthreads();
    }

    // epilogue: C layout col = lane&15, row = 4*(lane>>4)+r
    const int gr_base = m0 + wr * 64 + (lane >> 4) * 4;
    const int gc_base = n0 + wc * 64 + fr;
#pragma unroll
    for (int i = 0; i < 4; i++) {
#pragma unroll
        for (int j = 0; j < 4; j++) {
            const int col = gc_base + j * 16;
#pragma unroll
            for (int r = 0; r < 4; r++) {
                const int grow = gr_base + i * 16 + r;
                const int bb = grow >> 11;
                const int nn = grow & 2047;
                if (MODE == 0) {
                    const int sel = col >> 10;       // 0 = Q, 1 = K
                    const int cc = col & 1023;
                    const int hh = cc >> 6;
                    const int dd = cc & 63;
                    const float sc = sel ? 1.0f : QSCALE;
                    Cb[(((size_t)((sel << 6) + (bb << 4) + hh) * SEQ + nn) << 6) + dd] =
                        f2bf(acc[i][j][r] * sc);
                } else {
                    const int hh = col >> 6;
                    const float d = dgp[((bb << 4) + hh) * SEQ + nn];
                    out[(size_t)grow * EMB + col] = acc[i][j][r] * d;
                }
            }
        }
    }
}

// ---------------- diag kernel v5 ----------------------------------------
// Qh/Kh head-major [64][2048][64] bf16 (Q pre-scaled).
// Block = (bh, 128-q-row tile), 256 threads = 4 waves x 2 q-tiles (32 rows)
// each -> 4 B LDS traffic/score, grid = 64*16 = 1024 blocks (4/CU, 50% occ).
// Diag numerators from a global pre-pass; hot loop compare-free.
#define KT 128

__global__ __launch_bounds__(256, 4) void diag_kernel(const short* __restrict__ Qh,
                                                      const short* __restrict__ Kh,
                                                      float* __restrict__ dgp) {
    const int bh = blockIdx.x >> 4;     // 0..63
    const int qt = blockIdx.x & 15;     // 16 q-tiles of 128 rows
    __shared__ short Ks[2][KT][64];

    const int t = threadIdx.x;
    const int lane = t & 63;
    const int w = t >> 6;               // 0..3
    const int rl = lane & 15;
    const int g = lane >> 4;            // 0..3
    const int kq = g * 8;

    const short* Kbh = Kh + (size_t)bh * SEQ * DHEAD;
    const short* Qbh = Qh + (size_t)bh * SEQ * DHEAD;

    // Q fragments: 2 tiles of 16 rows (32 q-rows per wave)
    const int qbase = qt * 128 + w * 32;
    short8 a0[2], a1[2];
#pragma unroll
    for (int i = 0; i < 2; i++) {
        const int qrow = qbase + i * 16 + rl;
        a0[i] = *(const short8*)(Qbh + qrow * DHEAD + kq);
        a1[i] = *(const short8*)(Qbh + qrow * DHEAD + kq + 32);
    }

    // diag numerator pre-pass: K rows == Q rows for each tile
    float sdiag[2];
    const int rr = rl - g * 4;          // valid lane iff 0 <= rr < 4
#pragma unroll
    for (int i = 0; i < 2; i++) {
        const int krow = qbase + i * 16 + rl;
        const short8 b0d = *(const short8*)(Kbh + krow * DHEAD + kq);
        const short8 b1d = *(const short8*)(Kbh + krow * DHEAD + kq + 32);
        f32x4 cd = {};
        cd = __builtin_amdgcn_mfma_f32_16x16x32_bf16(a0[i], b0d, cd, 0, 0, 0);
        cd = __builtin_amdgcn_mfma_f32_16x16x32_bf16(a1[i], b1d, cd, 0, 0, 0);
        sdiag[i] = (rr >= 0 && rr < 4) ? cd[rr] : 0.f;
    }

    // staging map: 256 threads cover 128 rows x 8 16B-blocks, 4 blocks each
    const int sr = t >> 1;              // 0..127
    const int sh = (t & 1) * 4;         // 0 or 4

    // stage tile 0 (XOR-swizzled: block ^= row&7)
#pragma unroll
    for (int j = 0; j < 4; j++) {
        const int cb = sh + j;
        const int cs = (cb ^ (sr & 7)) * 8;
        *(short8*)&Ks[0][sr][cs] = *(const short8*)&Kbh[sr * DHEAD + cb * 8];
    }
    __syncthreads();

    // swizzled read blocks (row&7 == rl&7 == lane&7 since rows step by 16)
    const int blk0 = (g ^ (lane & 7)) * 8;
    const int blk1 = ((g + 4) ^ (lane & 7)) * 8;

    float ssum[2][4] = {};
    int buf = 0;

    for (int kt = 0; kt < SEQ / KT; ++kt) {
        short8 p[4];
        if (kt < SEQ / KT - 1) {
            const short* src = Kbh + (kt + 1) * KT * DHEAD;
#pragma unroll
            for (int j = 0; j < 4; j++)
                p[j] = *(const short8*)&src[sr * DHEAD + (sh + j) * 8];
        }
#pragma unroll
        for (int sub = 0; sub < 8; ++sub) {
            const int row = sub * 16 + rl;
            const short8 b0 = *(const short8*)&Ks[buf][row][blk0];
            const short8 b1 = *(const short8*)&Ks[buf][row][blk1];
            f32x4 c[2];
#pragma unroll
            for (int i = 0; i < 2; i++) {
                c[i] = __builtin_amdgcn_mfma_f32_16x16x32_bf16(a0[i], b0, f32x4{}, 0, 0, 0);
                c[i] = __builtin_amdgcn_mfma_f32_16x16x32_bf16(a1[i], b1, c[i], 0, 0, 0);
            }
#pragma unroll
            for (int i = 0; i < 2; i++)
#pragma unroll
                for (int r = 0; r < 4; ++r)
                    ssum[i][r] += __builtin_amdgcn_exp2f(c[i][r]);
        }
        if (kt < SEQ / KT - 1) {
            __syncthreads();
#pragma unroll
            for (int j = 0; j < 4; j++) {
                const int cb = sh + j;
                const int cs = (cb ^ (sr & 7)) * 8;
                *(short8*)&Ks[buf ^ 1][sr][cs] = p[j];
            }
            __syncthreads();
        }
        buf ^= 1;
    }

    // reduce partial sums across the 16-lane column groups
#pragma unroll
    for (int i = 0; i < 2; i++)
#pragma unroll
        for (int r = 0; r < 4; r++) {
            float v = ssum[i][r];
            v += __shfl_xor(v, 1);
            v += __shfl_xor(v, 2);
            v += __shfl_xor(v, 4);
            v += __shfl_xor(v, 8);
            ssum[i][r] = v;
        }

    if (rr >= 0 && rr < 4) {
#pragma unroll
        for (int i = 0; i < 2; i++) {
            const float dg = __builtin_amdgcn_exp2f(sdiag[i]) / ssum[i][rr];
            dgp[bh * SEQ + qbase + i * 16 + rl] = dg;
        }
    }
}

extern "C" void kernel_launch(void* const* d_in, const int* in_sizes, int n_in,
                              void* d_out, int out_size, void* d_ws, size_t ws_size,
                              hipStream_t stream) {
    const float* x  = (const float*)d_in[0];
    const float* Wq = (const float*)d_in[1];
    const float* Wk = (const float*)d_in[2];
    const float* Wv = (const float*)d_in[3];
    float* out = (float*)d_out;
    char* ws = (char*)d_ws;

    const size_t xb_off  = 0;
    const size_t wq_off  = xb_off + (size_t)MROWS * EMB * 2;
    const size_t wk_off  = wq_off + (size_t)EMB * EMB * 2;   // contiguous after wq
    const size_t wv_off  = wk_off + (size_t)EMB * EMB * 2;
    const size_t q_off   = wv_off + (size_t)EMB * EMB * 2;
    const size_t k_off   = q_off + (size_t)MROWS * EMB * 2;  // contiguous after q
    const size_t dg_off  = k_off + (size_t)MROWS * EMB * 2;

    short* xb  = (short*)(ws + xb_off);
    short* wqb = (short*)(ws + wq_off);
    short* wkb = (short*)(ws + wk_off);
    short* wvb = (short*)(ws + wv_off);
    short* Qh  = (short*)(ws + q_off);
    short* Kh  = (short*)(ws + k_off);
    float* dgp = (float*)(ws + dg_off);

    const int nx = MROWS * EMB;    // 8388608
    const int nw = EMB * EMB;      // 1048576

    pack_x<<<nx / 2048, 256, 0, stream>>>(x, (unsigned short*)xb,
                                          out + (size_t)MROWS * EMB);
    pack_w3<<<dim3(nw / 2048, 3), 256, 0, stream>>>(Wq, Wk, Wv,
                                                    (unsigned short*)wqb,
                                                    (unsigned short*)wkb,
                                                    (unsigned short*)wvb);

    // fused Q+K projection: B = [Wq | Wk] (contiguous), N = 2048
    gemm_bt<0><<<dim3(MROWS / 128, 2048 / 128), 256, 0, stream>>>(
        xb, wqb, (unsigned short*)Qh, nullptr, nullptr);

    diag_kernel<<<BATCH * HEADS * (SEQ / 128), 256, 0, stream>>>(Qh, Kh, dgp);

    gemm_bt<1><<<dim3(MROWS / 128, EMB / 128), 256, 0, stream>>>(
        xb, wvb, nullptr, out, dgp);
}

// Round 6
// 138.848 us; speedup vs baseline: 1.6709x; 1.6709x over previous
//
#include <hip/hip_runtime.h>
#include <hip/hip_bf16.h>
#include <stdint.h>

typedef __attribute__((ext_vector_type(8))) short short8;
typedef __attribute__((ext_vector_type(4))) float f32x4;

// Problem constants
#define BATCH 4
#define SEQ   2048
#define EMB   1024
#define HEADS 16
#define DHEAD 64
#define MROWS (BATCH * SEQ)   // 8192

// exp(s/8) == exp2(s * 0.125*log2(e)); fold into Q at bf16-pack time
#define QSCALE 0.18033688011112042f

__device__ inline unsigned short f2bf(float f) {
    unsigned int u = __float_as_uint(f);
    unsigned int r = (u + 0x7fffu + ((u >> 16) & 1u)) >> 16;
    return (unsigned short)r;
}

__device__ __forceinline__ void gl_lds16(const short* g, short* l) {
    __builtin_amdgcn_global_load_lds(
        (const __attribute__((address_space(1))) void*)g,
        (__attribute__((address_space(3))) void*)l, 16, 0, 0);
}

// ---------------- fused pack x -> bf16 + f32 passthrough ----------------
__global__ __launch_bounds__(256) void pack_x(const float* __restrict__ src,
                                              unsigned short* __restrict__ dst,
                                              float* __restrict__ pass) {
    int i = (blockIdx.x * 256 + threadIdx.x) * 8;
    const float4* s = reinterpret_cast<const float4*>(src + i);
    float4 f0 = s[0];
    float4 f1 = s[1];
    union { unsigned short u[8]; short8 v; } o;
    o.u[0] = f2bf(f0.x); o.u[1] = f2bf(f0.y); o.u[2] = f2bf(f0.z); o.u[3] = f2bf(f0.w);
    o.u[4] = f2bf(f1.x); o.u[5] = f2bf(f1.y); o.u[6] = f2bf(f1.z); o.u[7] = f2bf(f1.w);
    *reinterpret_cast<short8*>(dst + i) = o.v;
    float4* p = reinterpret_cast<float4*>(pass + i);
    p[0] = f0;
    p[1] = f1;
}

// ---------------- pack 3 weights -> bf16, one dispatch ----------------
__global__ __launch_bounds__(256) void pack_w3(const float* __restrict__ wq,
                                               const float* __restrict__ wk,
                                               const float* __restrict__ wv,
                                               unsigned short* __restrict__ dq,
                                               unsigned short* __restrict__ dk,
                                               unsigned short* __restrict__ dv) {
    const float* src = blockIdx.y == 0 ? wq : blockIdx.y == 1 ? wk : wv;
    unsigned short* dst = blockIdx.y == 0 ? dq : blockIdx.y == 1 ? dk : dv;
    int i = (blockIdx.x * 256 + threadIdx.x) * 8;
    const float4* s = reinterpret_cast<const float4*>(src + i);
    float4 f0 = s[0];
    float4 f1 = s[1];
    union { unsigned short u[8]; short8 v; } o;
    o.u[0] = f2bf(f0.x); o.u[1] = f2bf(f0.y); o.u[2] = f2bf(f0.z); o.u[3] = f2bf(f0.w);
    o.u[4] = f2bf(f1.x); o.u[5] = f2bf(f1.y); o.u[6] = f2bf(f1.z); o.u[7] = f2bf(f1.w);
    *reinterpret_cast<short8*>(dst + i) = o.v;
}

// ---------------- GEMM (m97 structure): C[m,e] = sum_k A[m,k]*B[e,k] ----
// MODE 0: fused QK — grid.y spans 2048 cols = [Wq | Wk]; store bf16
//         head-major [2*64][SEQ][64] (Qh then Kh), Q scaled by QSCALE.
// MODE 1: V — store f32 to out, scaled by diag.
template <int MODE>
__global__ __launch_bounds__(256) void gemm_bt(const short* __restrict__ A,
                                               const short* __restrict__ Bm,
                                               unsigned short* __restrict__ Cb,
                                               float* __restrict__ out,
                                               const float* __restrict__ dgp) {
    constexpr int K = EMB;
    __shared__ short As[128 * 32];   // linear: global_load_lds needs lane-contiguous dest
    __shared__ short Bs[128 * 32];
    const int m0 = blockIdx.x * 128;
    const int n0 = blockIdx.y * 128;
    const int t = threadIdx.x;
    const int lane = t & 63;
    const int w = t >> 6;                // 4 waves
    const int wr = w >> 1, wc = w & 1;   // 2x2 wave grid, 64x64 per wave

    f32x4 acc[4][4] = {};

    const short* gA = A + (size_t)(m0 + (t >> 2)) * K + (t & 3) * 8;
    const short* gB = Bm + (size_t)(n0 + (t >> 2)) * K + (t & 3) * 8;
    short* lA0 = As + w * 512;           // wave-uniform LDS bases
    short* lA1 = As + 2048 + w * 512;
    short* lB0 = Bs + w * 512;
    short* lB1 = Bs + 2048 + w * 512;

    const int kq = (lane >> 4) * 8;
    const int fr = lane & 15;

    for (int k0 = 0; k0 < K; k0 += 32) {
        gl_lds16(gA + k0, lA0);
        gl_lds16(gA + 64 * K + k0, lA1);
        gl_lds16(gB + k0, lB0);
        gl_lds16(gB + 64 * K + k0, lB1);
        __syncthreads();

        short8 a[4], b[4];
#pragma unroll
        for (int i = 0; i < 4; i++)
            a[i] = *(const short8*)&As[(wr * 64 + i * 16 + fr) * 32 + kq];
#pragma unroll
        for (int j = 0; j < 4; j++)
            b[j] = *(const short8*)&Bs[(wc * 64 + j * 16 + fr) * 32 + kq];
#pragma unroll
        for (int i = 0; i < 4; i++)
#pragma unroll
            for (int j = 0; j < 4; j++)
                acc[i][j] = __builtin_amdgcn_mfma_f32_16x16x32_bf16(a[i], b[j], acc[i][j], 0, 0, 0);
        __syncthreads();
    }

    // epilogue: C layout col = lane&15, row = 4*(lane>>4)+r
    const int gr_base = m0 + wr * 64 + (lane >> 4) * 4;
    const int gc_base = n0 + wc * 64 + fr;
#pragma unroll
    for (int i = 0; i < 4; i++) {
#pragma unroll
        for (int j = 0; j < 4; j++) {
            const int col = gc_base + j * 16;
#pragma unroll
            for (int r = 0; r < 4; r++) {
                const int grow = gr_base + i * 16 + r;
                const int bb = grow >> 11;
                const int nn = grow & 2047;
                if (MODE == 0) {
                    const int sel = col >> 10;       // 0 = Q, 1 = K
                    const int cc = col & 1023;
                    const int hh = cc >> 6;
                    const int dd = cc & 63;
                    const float sc = sel ? 1.0f : QSCALE;
                    Cb[(((size_t)((sel << 6) + (bb << 4) + hh) * SEQ + nn) << 6) + dd] =
                        f2bf(acc[i][j][r] * sc);
                } else {
                    const int hh = col >> 6;
                    const float d = dgp[((bb << 4) + hh) * SEQ + nn];
                    out[(size_t)grow * EMB + col] = acc[i][j][r] * d;
                }
            }
        }
    }
}

// ---------------- diag kernel v6 ----------------------------------------
// Qh/Kh head-major [64][2048][64] bf16 (Q pre-scaled).
// Block = (bh, 256-q-row tile): 512 threads = 8 waves x 32 q-rows.
// Grid 512 = 64 bh x 8 qt, XCD-swizzled: phys = (bh&7) + (bh>>3)*64 + qt*8
// so all 8 blocks of one bh share an XCD (under %8 round-robin AND /64
// chunk mappings) -> K re-reads hit that XCD's 4MB L2 (2MB working set).
#define KT 128

__global__ __launch_bounds__(512, 4) void diag_kernel(const short* __restrict__ Qh,
                                                      const short* __restrict__ Kh,
                                                      float* __restrict__ dgp) {
    const int n = blockIdx.x;
    const int bh = (n & 7) | ((n >> 6) << 3);   // 0..63
    const int qt = (n >> 3) & 7;                // 8 q-tiles of 256 rows
    __shared__ short Ks[2][KT][64];

    const int t = threadIdx.x;
    const int lane = t & 63;
    const int w = t >> 6;               // 0..7
    const int rl = lane & 15;
    const int g = lane >> 4;            // 0..3
    const int kq = g * 8;

    const short* Kbh = Kh + (size_t)bh * SEQ * DHEAD;
    const short* Qbh = Qh + (size_t)bh * SEQ * DHEAD;

    // Q fragments: 2 tiles of 16 rows (32 q-rows per wave)
    const int qbase = qt * 256 + w * 32;
    short8 a0[2], a1[2];
#pragma unroll
    for (int i = 0; i < 2; i++) {
        const int qrow = qbase + i * 16 + rl;
        a0[i] = *(const short8*)(Qbh + qrow * DHEAD + kq);
        a1[i] = *(const short8*)(Qbh + qrow * DHEAD + kq + 32);
    }

    // diag numerator pre-pass: K rows == Q rows for each tile
    float sdiag[2];
    const int rr = rl - g * 4;          // valid lane iff 0 <= rr < 4
#pragma unroll
    for (int i = 0; i < 2; i++) {
        const int krow = qbase + i * 16 + rl;
        const short8 b0d = *(const short8*)(Kbh + krow * DHEAD + kq);
        const short8 b1d = *(const short8*)(Kbh + krow * DHEAD + kq + 32);
        f32x4 cd = {};
        cd = __builtin_amdgcn_mfma_f32_16x16x32_bf16(a0[i], b0d, cd, 0, 0, 0);
        cd = __builtin_amdgcn_mfma_f32_16x16x32_bf16(a1[i], b1d, cd, 0, 0, 0);
        sdiag[i] = (rr >= 0 && rr < 4) ? cd[rr] : 0.f;
    }

    // staging map: 512 threads cover 128 rows x 8 16B-blocks, 2 slots each
    const int r0 = t >> 3;              // 0..63 (and +64)
    const int c0 = t & 7;               // 16B block
    const int cs = (c0 ^ (r0 & 7)) * 8; // XOR-swizzled (block ^= row&7)

    // stage tile 0
    *(short8*)&Ks[0][r0][cs]      = *(const short8*)&Kbh[r0 * DHEAD + c0 * 8];
    *(short8*)&Ks[0][r0 + 64][cs] = *(const short8*)&Kbh[(r0 + 64) * DHEAD + c0 * 8];
    __syncthreads();

    // swizzled read blocks (row&7 == rl&7 == lane&7 since rows step by 16)
    const int blk0 = (g ^ (lane & 7)) * 8;
    const int blk1 = ((g + 4) ^ (lane & 7)) * 8;

    float ssum[2][4] = {};
    int buf = 0;

    for (int kt = 0; kt < SEQ / KT; ++kt) {
        short8 p0, p1;
        if (kt < SEQ / KT - 1) {
            const short* src = Kbh + (kt + 1) * KT * DHEAD;
            p0 = *(const short8*)&src[r0 * DHEAD + c0 * 8];
            p1 = *(const short8*)&src[(r0 + 64) * DHEAD + c0 * 8];
        }
#pragma unroll
        for (int sub = 0; sub < 8; ++sub) {
            const int row = sub * 16 + rl;
            const short8 b0 = *(const short8*)&Ks[buf][row][blk0];
            const short8 b1 = *(const short8*)&Ks[buf][row][blk1];
            f32x4 c[2];
#pragma unroll
            for (int i = 0; i < 2; i++) {
                c[i] = __builtin_amdgcn_mfma_f32_16x16x32_bf16(a0[i], b0, f32x4{}, 0, 0, 0);
                c[i] = __builtin_amdgcn_mfma_f32_16x16x32_bf16(a1[i], b1, c[i], 0, 0, 0);
            }
#pragma unroll
            for (int i = 0; i < 2; i++)
#pragma unroll
                for (int r = 0; r < 4; ++r)
                    ssum[i][r] += __builtin_amdgcn_exp2f(c[i][r]);
        }
        if (kt < SEQ / KT - 1) {
            __syncthreads();
            *(short8*)&Ks[buf ^ 1][r0][cs]      = p0;
            *(short8*)&Ks[buf ^ 1][r0 + 64][cs] = p1;
            __syncthreads();
        }
        buf ^= 1;
    }

    // reduce partial sums across the 16-lane column groups
#pragma unroll
    for (int i = 0; i < 2; i++)
#pragma unroll
        for (int r = 0; r < 4; r++) {
            float v = ssum[i][r];
            v += __shfl_xor(v, 1);
            v += __shfl_xor(v, 2);
            v += __shfl_xor(v, 4);
            v += __shfl_xor(v, 8);
            ssum[i][r] = v;
        }

    if (rr >= 0 && rr < 4) {
#pragma unroll
        for (int i = 0; i < 2; i++) {
            const float dg = __builtin_amdgcn_exp2f(sdiag[i]) / ssum[i][rr];
            dgp[bh * SEQ + qbase + i * 16 + rl] = dg;
        }
    }
}

extern "C" void kernel_launch(void* const* d_in, const int* in_sizes, int n_in,
                              void* d_out, int out_size, void* d_ws, size_t ws_size,
                              hipStream_t stream) {
    const float* x  = (const float*)d_in[0];
    const float* Wq = (const float*)d_in[1];
    const float* Wk = (const float*)d_in[2];
    const float* Wv = (const float*)d_in[3];
    float* out = (float*)d_out;
    char* ws = (char*)d_ws;

    const size_t xb_off  = 0;
    const size_t wq_off  = xb_off + (size_t)MROWS * EMB * 2;
    const size_t wk_off  = wq_off + (size_t)EMB * EMB * 2;   // contiguous after wq
    const size_t wv_off  = wk_off + (size_t)EMB * EMB * 2;
    const size_t q_off   = wv_off + (size_t)EMB * EMB * 2;
    const size_t k_off   = q_off + (size_t)MROWS * EMB * 2;  // contiguous after q
    const size_t dg_off  = k_off + (size_t)MROWS * EMB * 2;

    short* xb  = (short*)(ws + xb_off);
    short* wqb = (short*)(ws + wq_off);
    short* wkb = (short*)(ws + wk_off);
    short* wvb = (short*)(ws + wv_off);
    short* Qh  = (short*)(ws + q_off);
    short* Kh  = (short*)(ws + k_off);
    float* dgp = (float*)(ws + dg_off);

    const int nx = MROWS * EMB;    // 8388608
    const int nw = EMB * EMB;      // 1048576

    pack_x<<<nx / 2048, 256, 0, stream>>>(x, (unsigned short*)xb,
                                          out + (size_t)MROWS * EMB);
    pack_w3<<<dim3(nw / 2048, 3), 256, 0, stream>>>(Wq, Wk, Wv,
                                                    (unsigned short*)wqb,
                                                    (unsigned short*)wkb,
                                                    (unsigned short*)wvb);

    // fused Q+K projection: B = [Wq | Wk] (contiguous), N = 2048
    gemm_bt<0><<<dim3(MROWS / 128, 2048 / 128), 256, 0, stream>>>(
        xb, wqb, (unsigned short*)Qh, nullptr, nullptr);

    diag_kernel<<<BATCH * HEADS * (SEQ / 256), 512, 0, stream>>>(Qh, Kh, dgp);

    gemm_bt<1><<<dim3(MROWS / 128, EMB / 128), 256, 0, stream>>>(
        xb, wvb, nullptr, out, dgp);
}

// Round 7
// 129.323 us; speedup vs baseline: 1.7940x; 1.0736x over previous
//
#include <hip/hip_runtime.h>
#include <hip/hip_bf16.h>
#include <stdint.h>

typedef __attribute__((ext_vector_type(8))) short short8;
typedef __attribute__((ext_vector_type(4))) float f32x4;

// Problem constants
#define BATCH 4
#define SEQ   2048
#define EMB   1024
#define HEADS 16
#define DHEAD 64
#define MROWS (BATCH * SEQ)   // 8192

// exp(s/8) == exp2(s * 0.125*log2(e)); fold into Q at bf16-pack time
#define QSCALE 0.18033688011112042f

__device__ inline unsigned short f2bf(float f) {
    unsigned int u = __float_as_uint(f);
    unsigned int r = (u + 0x7fffu + ((u >> 16) & 1u)) >> 16;
    return (unsigned short)r;
}

__device__ __forceinline__ void gl_lds16(const short* g, short* l) {
    __builtin_amdgcn_global_load_lds(
        (const __attribute__((address_space(1))) void*)g,
        (__attribute__((address_space(3))) void*)l, 16, 0, 0);
}

template <int N>
__device__ __forceinline__ void waitvm() {
    asm volatile("s_waitcnt vmcnt(%0)" :: "n"(N) : "memory");
}

// ---------------- fused pack x -> bf16 + f32 passthrough ----------------
__global__ __launch_bounds__(256) void pack_x(const float* __restrict__ src,
                                              unsigned short* __restrict__ dst,
                                              float* __restrict__ pass) {
    int i = (blockIdx.x * 256 + threadIdx.x) * 8;
    const float4* s = reinterpret_cast<const float4*>(src + i);
    float4 f0 = s[0];
    float4 f1 = s[1];
    union { unsigned short u[8]; short8 v; } o;
    o.u[0] = f2bf(f0.x); o.u[1] = f2bf(f0.y); o.u[2] = f2bf(f0.z); o.u[3] = f2bf(f0.w);
    o.u[4] = f2bf(f1.x); o.u[5] = f2bf(f1.y); o.u[6] = f2bf(f1.z); o.u[7] = f2bf(f1.w);
    *reinterpret_cast<short8*>(dst + i) = o.v;
    float4* p = reinterpret_cast<float4*>(pass + i);
    p[0] = f0;
    p[1] = f1;
}

// ---------------- pack 3 weights -> bf16, one dispatch ----------------
__global__ __launch_bounds__(256) void pack_w3(const float* __restrict__ wq,
                                               const float* __restrict__ wk,
                                               const float* __restrict__ wv,
                                               unsigned short* __restrict__ dq,
                                               unsigned short* __restrict__ dk,
                                               unsigned short* __restrict__ dv) {
    const float* src = blockIdx.y == 0 ? wq : blockIdx.y == 1 ? wk : wv;
    unsigned short* dst = blockIdx.y == 0 ? dq : blockIdx.y == 1 ? dk : dv;
    int i = (blockIdx.x * 256 + threadIdx.x) * 8;
    const float4* s = reinterpret_cast<const float4*>(src + i);
    float4 f0 = s[0];
    float4 f1 = s[1];
    union { unsigned short u[8]; short8 v; } o;
    o.u[0] = f2bf(f0.x); o.u[1] = f2bf(f0.y); o.u[2] = f2bf(f0.z); o.u[3] = f2bf(f0.w);
    o.u[4] = f2bf(f1.x); o.u[5] = f2bf(f1.y); o.u[6] = f2bf(f1.z); o.u[7] = f2bf(f1.w);
    *reinterpret_cast<short8*>(dst + i) = o.v;
}

// ---------------- 8-wave 256-wide pipelined GEMM ------------------------
// C[m,n] = sum_k A[m,k] * B[n,k]  (NT, bf16 in), K = 1024, BK = 32.
// 512 threads = 8 waves in a 2(M) x 4(N) grid; per-wave 128 x BN/4 output.
// 3 LDS buffers (one K-tile each), 2-tile-deep prefetch via global_load_lds,
// one raw s_barrier + counted vmcnt per K-tile (T3+T4), setprio on MFMA (T5).
// LDS granule XOR-swizzle (T2): logical granule g of row r stored at
// physical g^(r&3); staging pre-swizzles the GLOBAL source (rule #21).
// MODE 0: BN=256, cols span [Wq|Wk]; bf16 head-major out, Q scaled QSCALE.
// MODE 1: BN=128, f32 out scaled by diag.
template <int MODE>
__global__ __launch_bounds__(512, 2) void gemm8(const short* __restrict__ A,
                                                const short* __restrict__ Bm,
                                                unsigned short* __restrict__ Cb,
                                                float* __restrict__ out,
                                                const float* __restrict__ dgp) {
    constexpr int K = EMB;
    constexpr int NT = K / 32;                 // 32 K-tiles
    constexpr int BN = (MODE == 0) ? 256 : 128;
    constexpr int NF = BN / 64;                // N-frags per wave: 4 or 2
    constexpr int BUFSTRIDE = 8192 + BN * 32;  // shorts per buffer
    constexpr int VW = 2 + BN / 128;           // vmem ops per wave per tile: 4 or 3

    __shared__ short Ks[3 * BUFSTRIDE];        // 96 KB (MODE0) / 72 KB (MODE1)

    const int t = threadIdx.x;
    const int lane = t & 63;
    const int w = t >> 6;            // 0..7
    const int wr = w >> 2;           // 0..1   M half
    const int wc = w & 3;            // 0..3   N quarter
    const int rl = lane & 15;
    const int pg = (lane >> 4) ^ (lane & 3);   // swizzled read granule
    const int m0 = blockIdx.x * 256;
    const int n0 = blockIdx.y * BN;

    // staging: thread t sources granule (r, g) with r=t>>2, g=(t&3)^(r&3);
    // LDS dest is linear (granule index t), so LDS holds g at phys g^(r&3).
    const int sr = t >> 2;                     // 0..127
    const int sg = (t & 3) ^ (sr & 3);
    const int soff = sr * K + sg * 8;
    const short* gA0 = A + (size_t)(m0)*K + soff;
    const short* gA1 = A + (size_t)(m0 + 128) * K + soff;
    const short* gB0 = Bm + (size_t)(n0)*K + soff;
    const short* gB1 = Bm + (size_t)(n0 + 128) * K + soff;  // MODE0 only
    short* ldsw = Ks + w * 512;                // wave-uniform stage base

#define STAGE8(kk, bb)                                               \
    {                                                                \
        const int _k = (kk)*32;                                      \
        short* _l = ldsw + (bb)*BUFSTRIDE;                           \
        gl_lds16(gA0 + _k, _l);                                      \
        gl_lds16(gA1 + _k, _l + 4096);                               \
        gl_lds16(gB0 + _k, _l + 8192);                               \
        if (MODE == 0) gl_lds16(gB1 + _k, _l + 12288);               \
    }

    f32x4 acc[8][NF] = {};

    // prologue: tiles 0,1 -> bufs 0,1
    STAGE8(0, 0);
    STAGE8(1, 1);
    waitvm<VW>();                    // tile 0 landed
    __builtin_amdgcn_s_barrier();

    int cur = 0;
    for (int kt = 0; kt < NT; ++kt) {
        const int pf = kt + 2;
        if (pf < NT) {
            int nb = cur + 2; if (nb >= 3) nb -= 3;
            STAGE8(pf, nb);
        }

        const short* bufp = Ks + cur * BUFSTRIDE;
        short8 av[8], bv[NF];
#pragma unroll
        for (int i = 0; i < 8; i++)
            av[i] = *(const short8*)&bufp[wr * 4096 + i * 512 + rl * 32 + pg * 8];
#pragma unroll
        for (int j = 0; j < NF; j++) {
            const int brow = (MODE == 0) ? ((wc & 1) * 64 + j * 16 + rl)
                                         : (wc * 32 + j * 16 + rl);
            const int bh = (MODE == 0) ? (wc >> 1) : 0;
            bv[j] = *(const short8*)&bufp[8192 + bh * 4096 + brow * 32 + pg * 8];
        }

        __builtin_amdgcn_s_setprio(1);
#pragma unroll
        for (int i = 0; i < 8; i++)
#pragma unroll
            for (int j = 0; j < NF; j++)
                acc[i][j] = __builtin_amdgcn_mfma_f32_16x16x32_bf16(av[i], bv[j], acc[i][j], 0, 0, 0);
        __builtin_amdgcn_s_setprio(0);

        if (kt < NT - 2) waitvm<VW>();   // next tile landed; prefetch stays in flight
        else             waitvm<0>();
        __builtin_amdgcn_s_barrier();

        cur += 1; if (cur == 3) cur = 0;
    }
#undef STAGE8

    // epilogue: C layout col = lane&15, row = 4*(lane>>4)+r
    const int gr_base = m0 + wr * 128 + (lane >> 4) * 4;
    const int gc_base = n0 + wc * (BN / 4) + rl;
#pragma unroll
    for (int i = 0; i < 8; i++) {
#pragma unroll
        for (int j = 0; j < NF; j++) {
            const int col = gc_base + j * 16;
#pragma unroll
            for (int r = 0; r < 4; r++) {
                const int grow = gr_base + i * 16 + r;
                const int bb = grow >> 11;
                const int nn = grow & 2047;
                if (MODE == 0) {
                    const int sel = col >> 10;       // 0 = Q, 1 = K
                    const int cc = col & 1023;
                    const int hh = cc >> 6;
                    const int dd = cc & 63;
                    const float sc = sel ? 1.0f : QSCALE;
                    Cb[(((size_t)((sel << 6) + (bb << 4) + hh) * SEQ + nn) << 6) + dd] =
                        f2bf(acc[i][j][r] * sc);
                } else {
                    const int hh = col >> 6;
                    const float d = dgp[((bb << 4) + hh) * SEQ + nn];
                    out[(size_t)grow * EMB + col] = acc[i][j][r] * d;
                }
            }
        }
    }
}

// ---------------- diag kernel v6 (unchanged) -----------------------------
#define KT 128

__global__ __launch_bounds__(512, 4) void diag_kernel(const short* __restrict__ Qh,
                                                      const short* __restrict__ Kh,
                                                      float* __restrict__ dgp) {
    const int n = blockIdx.x;
    const int bh = (n & 7) | ((n >> 6) << 3);   // 0..63
    const int qt = (n >> 3) & 7;                // 8 q-tiles of 256 rows
    __shared__ short Ksd[2][KT][64];

    const int t = threadIdx.x;
    const int lane = t & 63;
    const int w = t >> 6;               // 0..7
    const int rl = lane & 15;
    const int g = lane >> 4;            // 0..3
    const int kq = g * 8;

    const short* Kbh = Kh + (size_t)bh * SEQ * DHEAD;
    const short* Qbh = Qh + (size_t)bh * SEQ * DHEAD;

    const int qbase = qt * 256 + w * 32;
    short8 a0[2], a1[2];
#pragma unroll
    for (int i = 0; i < 2; i++) {
        const int qrow = qbase + i * 16 + rl;
        a0[i] = *(const short8*)(Qbh + qrow * DHEAD + kq);
        a1[i] = *(const short8*)(Qbh + qrow * DHEAD + kq + 32);
    }

    float sdiag[2];
    const int rr = rl - g * 4;
#pragma unroll
    for (int i = 0; i < 2; i++) {
        const int krow = qbase + i * 16 + rl;
        const short8 b0d = *(const short8*)(Kbh + krow * DHEAD + kq);
        const short8 b1d = *(const short8*)(Kbh + krow * DHEAD + kq + 32);
        f32x4 cd = {};
        cd = __builtin_amdgcn_mfma_f32_16x16x32_bf16(a0[i], b0d, cd, 0, 0, 0);
        cd = __builtin_amdgcn_mfma_f32_16x16x32_bf16(a1[i], b1d, cd, 0, 0, 0);
        sdiag[i] = (rr >= 0 && rr < 4) ? cd[rr] : 0.f;
    }

    const int r0 = t >> 3;
    const int c0 = t & 7;
    const int cs = (c0 ^ (r0 & 7)) * 8;

    *(short8*)&Ksd[0][r0][cs]      = *(const short8*)&Kbh[r0 * DHEAD + c0 * 8];
    *(short8*)&Ksd[0][r0 + 64][cs] = *(const short8*)&Kbh[(r0 + 64) * DHEAD + c0 * 8];
    __syncthreads();

    const int blk0 = (g ^ (lane & 7)) * 8;
    const int blk1 = ((g + 4) ^ (lane & 7)) * 8;

    float ssum[2][4] = {};
    int buf = 0;

    for (int kt = 0; kt < SEQ / KT; ++kt) {
        short8 p0, p1;
        if (kt < SEQ / KT - 1) {
            const short* src = Kbh + (kt + 1) * KT * DHEAD;
            p0 = *(const short8*)&src[r0 * DHEAD + c0 * 8];
            p1 = *(const short8*)&src[(r0 + 64) * DHEAD + c0 * 8];
        }
#pragma unroll
        for (int sub = 0; sub < 8; ++sub) {
            const int row = sub * 16 + rl;
            const short8 b0 = *(const short8*)&Ksd[buf][row][blk0];
            const short8 b1 = *(const short8*)&Ksd[buf][row][blk1];
            f32x4 c[2];
#pragma unroll
            for (int i = 0; i < 2; i++) {
                c[i] = __builtin_amdgcn_mfma_f32_16x16x32_bf16(a0[i], b0, f32x4{}, 0, 0, 0);
                c[i] = __builtin_amdgcn_mfma_f32_16x16x32_bf16(a1[i], b1, c[i], 0, 0, 0);
            }
#pragma unroll
            for (int i = 0; i < 2; i++)
#pragma unroll
                for (int r = 0; r < 4; ++r)
                    ssum[i][r] += __builtin_amdgcn_exp2f(c[i][r]);
        }
        if (kt < SEQ / KT - 1) {
            __syncthreads();
            *(short8*)&Ksd[buf ^ 1][r0][cs]      = p0;
            *(short8*)&Ksd[buf ^ 1][r0 + 64][cs] = p1;
            __syncthreads();
        }
        buf ^= 1;
    }

#pragma unroll
    for (int i = 0; i < 2; i++)
#pragma unroll
        for (int r = 0; r < 4; r++) {
            float v = ssum[i][r];
            v += __shfl_xor(v, 1);
            v += __shfl_xor(v, 2);
            v += __shfl_xor(v, 4);
            v += __shfl_xor(v, 8);
            ssum[i][r] = v;
        }

    if (rr >= 0 && rr < 4) {
#pragma unroll
        for (int i = 0; i < 2; i++) {
            const float dg = __builtin_amdgcn_exp2f(sdiag[i]) / ssum[i][rr];
            dgp[bh * SEQ + qbase + i * 16 + rl] = dg;
        }
    }
}

extern "C" void kernel_launch(void* const* d_in, const int* in_sizes, int n_in,
                              void* d_out, int out_size, void* d_ws, size_t ws_size,
                              hipStream_t stream) {
    const float* x  = (const float*)d_in[0];
    const float* Wq = (const float*)d_in[1];
    const float* Wk = (const float*)d_in[2];
    const float* Wv = (const float*)d_in[3];
    float* out = (float*)d_out;
    char* ws = (char*)d_ws;

    const size_t xb_off  = 0;
    const size_t wq_off  = xb_off + (size_t)MROWS * EMB * 2;
    const size_t wk_off  = wq_off + (size_t)EMB * EMB * 2;   // contiguous after wq
    const size_t wv_off  = wk_off + (size_t)EMB * EMB * 2;
    const size_t q_off   = wv_off + (size_t)EMB * EMB * 2;
    const size_t k_off   = q_off + (size_t)MROWS * EMB * 2;  // contiguous after q
    const size_t dg_off  = k_off + (size_t)MROWS * EMB * 2;

    short* xb  = (short*)(ws + xb_off);
    short* wqb = (short*)(ws + wq_off);
    short* wkb = (short*)(ws + wk_off);
    short* wvb = (short*)(ws + wv_off);
    short* Qh  = (short*)(ws + q_off);
    short* Kh  = (short*)(ws + k_off);
    float* dgp = (float*)(ws + dg_off);

    const int nx = MROWS * EMB;    // 8388608
    const int nw = EMB * EMB;      // 1048576

    pack_x<<<nx / 2048, 256, 0, stream>>>(x, (unsigned short*)xb,
                                          out + (size_t)MROWS * EMB);
    pack_w3<<<dim3(nw / 2048, 3), 256, 0, stream>>>(Wq, Wk, Wv,
                                                    (unsigned short*)wqb,
                                                    (unsigned short*)wkb,
                                                    (unsigned short*)wvb);

    // fused Q+K projection: B = [Wq | Wk] (contiguous), N = 2048
    gemm8<0><<<dim3(MROWS / 256, 2048 / 256), 512, 0, stream>>>(
        xb, wqb, (unsigned short*)Qh, nullptr, nullptr);

    diag_kernel<<<BATCH * HEADS * (SEQ / 256), 512, 0, stream>>>(Qh, Kh, dgp);

    gemm8<1><<<dim3(MROWS / 256, EMB / 128), 512, 0, stream>>>(
        xb, wvb, nullptr, out, dgp);
}

// Round 8
// 128.917 us; speedup vs baseline: 1.7996x; 1.0032x over previous
//
#include <hip/hip_runtime.h>
#include <hip/hip_bf16.h>
#include <stdint.h>

typedef __attribute__((ext_vector_type(8))) short short8;
typedef __attribute__((ext_vector_type(4))) float f32x4;

// Problem constants
#define BATCH 4
#define SEQ   2048
#define EMB   1024
#define HEADS 16
#define DHEAD 64
#define MROWS (BATCH * SEQ)   // 8192
#define NW    (EMB * EMB)     // 1048576

// exp(s/8) == exp2(s * 0.125*log2(e)); fold into Q at bf16-pack time
#define QSCALE 0.18033688011112042f

__device__ inline unsigned short f2bf(float f) {
    unsigned int u = __float_as_uint(f);
    unsigned int r = (u + 0x7fffu + ((u >> 16) & 1u)) >> 16;
    return (unsigned short)r;
}

__device__ __forceinline__ void gl_lds16(const short* g, short* l) {
    __builtin_amdgcn_global_load_lds(
        (const __attribute__((address_space(1))) void*)g,
        (__attribute__((address_space(3))) void*)l, 16, 0, 0);
}

template <int N>
__device__ __forceinline__ void waitvm() {
    asm volatile("s_waitcnt vmcnt(%0)" :: "n"(N) : "memory");
}

// ------- fused pack: x -> bf16 + f32 passthrough, and Wq|Wk|Wv -> bf16 ---
// Flat index space over [x | wq | wk | wv]; wqb/wkb/wvb are contiguous.
__global__ __launch_bounds__(256) void pack_all(const float* __restrict__ x,
                                                const float* __restrict__ wq,
                                                const float* __restrict__ wk,
                                                const float* __restrict__ wv,
                                                unsigned short* __restrict__ xb,
                                                unsigned short* __restrict__ wb,
                                                float* __restrict__ pass) {
    const int i = (blockIdx.x * 256 + threadIdx.x) * 8;
    const float* src;
    unsigned short* dst;
    bool isx = i < MROWS * EMB;
    if (isx) {
        src = x + i;
        dst = xb + i;
    } else {
        const int j = i - MROWS * EMB;
        src = (j < NW) ? wq + j : (j < 2 * NW) ? wk + (j - NW) : wv + (j - 2 * NW);
        dst = wb + j;
    }
    const float4* s = reinterpret_cast<const float4*>(src);
    float4 f0 = s[0];
    float4 f1 = s[1];
    union { unsigned short u[8]; short8 v; } o;
    o.u[0] = f2bf(f0.x); o.u[1] = f2bf(f0.y); o.u[2] = f2bf(f0.z); o.u[3] = f2bf(f0.w);
    o.u[4] = f2bf(f1.x); o.u[5] = f2bf(f1.y); o.u[6] = f2bf(f1.z); o.u[7] = f2bf(f1.w);
    *reinterpret_cast<short8*>(dst) = o.v;
    if (isx) {
        float4* p = reinterpret_cast<float4*>(pass + i);
        p[0] = f0;
        p[1] = f1;
    }
}

// ---------------- 8-wave 256-wide pipelined GEMM ------------------------
// C[m,n] = sum_k A[m,k] * B[n,k]  (NT, bf16 in), K = 1024, BK = 32.
// 512 threads = 8 waves in a 2(M) x 4(N) grid; per-wave 128 x BN/4 output.
// 3 LDS buffers, 2-tile-deep prefetch via global_load_lds, one raw
// s_barrier + counted vmcnt per K-tile (T3+T4), setprio on MFMA (T5).
// LDS granule XOR-swizzle (T2) via pre-swizzled global source (rule #21).
// MODE 0: BN=256, cols span [Wq|Wk]; bf16 head-major out, Q scaled QSCALE.
// MODE 1: BN=128, f32 out scaled by diag.
template <int MODE>
__global__ __launch_bounds__(512, 2) void gemm8(const short* __restrict__ A,
                                                const short* __restrict__ Bm,
                                                unsigned short* __restrict__ Cb,
                                                float* __restrict__ out,
                                                const float* __restrict__ dgp) {
    constexpr int K = EMB;
    constexpr int NT = K / 32;                 // 32 K-tiles
    constexpr int BN = (MODE == 0) ? 256 : 128;
    constexpr int NF = BN / 64;                // N-frags per wave: 4 or 2
    constexpr int BUFSTRIDE = 8192 + BN * 32;  // shorts per buffer
    constexpr int VW = 2 + BN / 128;           // vmem ops per wave per tile: 4 or 3

    __shared__ short Ks[3 * BUFSTRIDE];        // 96 KB (MODE0) / 72 KB (MODE1)

    const int t = threadIdx.x;
    const int lane = t & 63;
    const int w = t >> 6;            // 0..7
    const int wr = w >> 2;           // 0..1   M half
    const int wc = w & 3;            // 0..3   N quarter
    const int rl = lane & 15;
    const int pg = (lane >> 4) ^ (lane & 3);   // swizzled read granule
    const int m0 = blockIdx.x * 256;
    const int n0 = blockIdx.y * BN;

    const int sr = t >> 2;                     // 0..127
    const int sg = (t & 3) ^ (sr & 3);
    const int soff = sr * K + sg * 8;
    const short* gA0 = A + (size_t)(m0)*K + soff;
    const short* gA1 = A + (size_t)(m0 + 128) * K + soff;
    const short* gB0 = Bm + (size_t)(n0)*K + soff;
    const short* gB1 = Bm + (size_t)(n0 + 128) * K + soff;  // MODE0 only
    short* ldsw = Ks + w * 512;                // wave-uniform stage base

#define STAGE8(kk, bb)                                               \
    {                                                                \
        const int _k = (kk)*32;                                      \
        short* _l = ldsw + (bb)*BUFSTRIDE;                           \
        gl_lds16(gA0 + _k, _l);                                      \
        gl_lds16(gA1 + _k, _l + 4096);                               \
        gl_lds16(gB0 + _k, _l + 8192);                               \
        if (MODE == 0) gl_lds16(gB1 + _k, _l + 12288);               \
    }

    f32x4 acc[8][NF] = {};

    // prologue: tiles 0,1 -> bufs 0,1
    STAGE8(0, 0);
    STAGE8(1, 1);
    waitvm<VW>();                    // tile 0 landed
    __builtin_amdgcn_s_barrier();

    int cur = 0;
    for (int kt = 0; kt < NT; ++kt) {
        const int pf = kt + 2;
        if (pf < NT) {
            int nb = cur + 2; if (nb >= 3) nb -= 3;
            STAGE8(pf, nb);
        }

        const short* bufp = Ks + cur * BUFSTRIDE;
        short8 av[8], bv[NF];
#pragma unroll
        for (int i = 0; i < 8; i++)
            av[i] = *(const short8*)&bufp[wr * 4096 + i * 512 + rl * 32 + pg * 8];
#pragma unroll
        for (int j = 0; j < NF; j++) {
            const int brow = (MODE == 0) ? ((wc & 1) * 64 + j * 16 + rl)
                                         : (wc * 32 + j * 16 + rl);
            const int bh = (MODE == 0) ? (wc >> 1) : 0;
            bv[j] = *(const short8*)&bufp[8192 + bh * 4096 + brow * 32 + pg * 8];
        }

        __builtin_amdgcn_s_setprio(1);
#pragma unroll
        for (int i = 0; i < 8; i++)
#pragma unroll
            for (int j = 0; j < NF; j++)
                acc[i][j] = __builtin_amdgcn_mfma_f32_16x16x32_bf16(av[i], bv[j], acc[i][j], 0, 0, 0);
        __builtin_amdgcn_s_setprio(0);

        if (kt < NT - 2) waitvm<VW>();   // next tile landed; prefetch stays in flight
        else             waitvm<0>();
        __builtin_amdgcn_s_barrier();

        cur += 1; if (cur == 3) cur = 0;
    }
#undef STAGE8

    // epilogue: C layout col = lane&15, row = 4*(lane>>4)+r
    const int gr_base = m0 + wr * 128 + (lane >> 4) * 4;
    const int gc_base = n0 + wc * (BN / 4) + rl;
#pragma unroll
    for (int i = 0; i < 8; i++) {
#pragma unroll
        for (int j = 0; j < NF; j++) {
            const int col = gc_base + j * 16;
#pragma unroll
            for (int r = 0; r < 4; r++) {
                const int grow = gr_base + i * 16 + r;
                const int bb = grow >> 11;
                const int nn = grow & 2047;
                if (MODE == 0) {
                    const int sel = col >> 10;       // 0 = Q, 1 = K
                    const int cc = col & 1023;
                    const int hh = cc >> 6;
                    const int dd = cc & 63;
                    const float sc = sel ? 1.0f : QSCALE;
                    Cb[(((size_t)((sel << 6) + (bb << 4) + hh) * SEQ + nn) << 6) + dd] =
                        f2bf(acc[i][j][r] * sc);
                } else {
                    const int hh = col >> 6;
                    const float d = dgp[((bb << 4) + hh) * SEQ + nn];
                    out[(size_t)grow * EMB + col] = acc[i][j][r] * d;
                }
            }
        }
    }
}

// ---------------- diag kernel v7 ----------------------------------------
// Qh/Kh head-major [64][2048][64] bf16 (Q pre-scaled by QSCALE).
// Block = (bh, 256-q-row tile): 512 threads = 8 waves x 32 q-rows.
// XCD-pinned grid (all 8 blocks of one bh on one XCD -> K hits L2).
// K staged via global_load_lds with pre-swizzled global source (rule #21),
// 3 LDS buffers, depth-2 prefetch, counted vmcnt(2), ONE barrier per tile.
// exp2 accumulation software-pipelined 2-deep (cE/cO) against the MFMAs.
#define DNT (SEQ / 128)   // 16 k-tiles of 128 rows

__global__ __launch_bounds__(512, 4) void diag_kernel(const short* __restrict__ Qh,
                                                      const short* __restrict__ Kh,
                                                      float* __restrict__ dgp) {
    const int n = blockIdx.x;
    const int bh = (n & 7) | ((n >> 6) << 3);   // 0..63
    const int qt = (n >> 3) & 7;                // 8 q-tiles of 256 rows
    __shared__ short Ksd[3 * 8192];             // 3 bufs x 128 rows x 64

    const int t = threadIdx.x;
    const int lane = t & 63;
    const int w = t >> 6;               // 0..7
    const int rl = lane & 15;
    const int g = lane >> 4;            // 0..3
    const int kq = g * 8;

    const short* Kbh = Kh + (size_t)bh * SEQ * DHEAD;
    const short* Qbh = Qh + (size_t)bh * SEQ * DHEAD;

    // Q fragments: 2 tiles of 16 rows (32 q-rows per wave)
    const int qbase = qt * 256 + w * 32;
    short8 a0[2], a1[2];
#pragma unroll
    for (int i = 0; i < 2; i++) {
        const int qrow = qbase + i * 16 + rl;
        a0[i] = *(const short8*)(Qbh + qrow * DHEAD + kq);
        a1[i] = *(const short8*)(Qbh + qrow * DHEAD + kq + 32);
    }

    // diag numerator pre-pass (global K reads; consumed before staging)
    float sdiag[2];
    const int rr = rl - g * 4;          // valid lane iff 0 <= rr < 4
#pragma unroll
    for (int i = 0; i < 2; i++) {
        const int krow = qbase + i * 16 + rl;
        const short8 b0d = *(const short8*)(Kbh + krow * DHEAD + kq);
        const short8 b1d = *(const short8*)(Kbh + krow * DHEAD + kq + 32);
        f32x4 cd = {};
        cd = __builtin_amdgcn_mfma_f32_16x16x32_bf16(a0[i], b0d, cd, 0, 0, 0);
        cd = __builtin_amdgcn_mfma_f32_16x16x32_bf16(a1[i], b1d, cd, 0, 0, 0);
        sdiag[i] = (rr >= 0 && rr < 4) ? cd[rr] : 0.f;
    }

    // staging: thread t sources granule (row t>>3, block (t&7)^(row&7));
    // LDS dest linear (granule t) => LDS holds logical block b at b^(row&7).
    const int sr = t >> 3;              // 0..63
    const int sb = ((t & 7) ^ (sr & 7)) * 8;
    const short* gK0 = Kbh + sr * DHEAD + sb;
    const short* gK1 = Kbh + (sr + 64) * DHEAD + sb;
    short* ldsw = Ksd + w * 512;        // wave-uniform stage base

#define DSTAGE(kk, bb)                                    \
    {                                                     \
        gl_lds16(gK0 + (kk)*8192, ldsw + (bb)*8192);      \
        gl_lds16(gK1 + (kk)*8192, ldsw + (bb)*8192 + 4096); \
    }

    // swizzled read blocks (row&7 == lane&7 since rows step by 16)
    const int blk0 = (g ^ (lane & 7)) * 8;
    const int blk1 = ((g + 4) ^ (lane & 7)) * 8;

    float ssum[2][4] = {};

    DSTAGE(0, 0);
    DSTAGE(1, 1);
    waitvm<2>();                        // tile 0 landed
    __builtin_amdgcn_s_barrier();

#define QKMFMA(sub, c)                                                          \
    {                                                                           \
        const short* _r = bufp + ((sub)*16 + rl) * 64;                          \
        const short8 _b0 = *(const short8*)(_r + blk0);                         \
        const short8 _b1 = *(const short8*)(_r + blk1);                         \
        c[0] = __builtin_amdgcn_mfma_f32_16x16x32_bf16(a0[0], _b0, f32x4{}, 0, 0, 0); \
        c[0] = __builtin_amdgcn_mfma_f32_16x16x32_bf16(a1[0], _b1, c[0], 0, 0, 0);    \
        c[1] = __builtin_amdgcn_mfma_f32_16x16x32_bf16(a0[1], _b0, f32x4{}, 0, 0, 0); \
        c[1] = __builtin_amdgcn_mfma_f32_16x16x32_bf16(a1[1], _b1, c[1], 0, 0, 0);    \
    }
#define EXPACC(c)                                         \
    {                                                     \
        _Pragma("unroll") for (int i = 0; i < 2; i++)     \
        _Pragma("unroll") for (int r = 0; r < 4; ++r)     \
            ssum[i][r] += __builtin_amdgcn_exp2f(c[i][r]); \
    }

    int cur = 0;
    for (int kt = 0; kt < DNT; ++kt) {
        if (kt + 2 < DNT) {
            int nb = cur + 2; if (nb >= 3) nb -= 3;
            DSTAGE(kt + 2, nb);
        }
        const short* bufp = Ksd + cur * 8192;

        f32x4 cE[2], cO[2];
        QKMFMA(0, cE);
        QKMFMA(1, cO);
        EXPACC(cE);
        QKMFMA(2, cE);
        EXPACC(cO);
        QKMFMA(3, cO);
        EXPACC(cE);
        QKMFMA(4, cE);
        EXPACC(cO);
        QKMFMA(5, cO);
        EXPACC(cE);
        QKMFMA(6, cE);
        EXPACC(cO);
        QKMFMA(7, cO);
        EXPACC(cE);
        EXPACC(cO);

        if (kt < DNT - 1) {
            if (kt < DNT - 2) waitvm<2>();
            else              waitvm<0>();
            __builtin_amdgcn_s_barrier();
        }
        cur += 1; if (cur == 3) cur = 0;
    }
#undef DSTAGE
#undef QKMFMA
#undef EXPACC

    // reduce partial sums across the 16-lane column groups
#pragma unroll
    for (int i = 0; i < 2; i++)
#pragma unroll
        for (int r = 0; r < 4; r++) {
            float v = ssum[i][r];
            v += __shfl_xor(v, 1);
            v += __shfl_xor(v, 2);
            v += __shfl_xor(v, 4);
            v += __shfl_xor(v, 8);
            ssum[i][r] = v;
        }

    if (rr >= 0 && rr < 4) {
#pragma unroll
        for (int i = 0; i < 2; i++) {
            const float dg = __builtin_amdgcn_exp2f(sdiag[i]) / ssum[i][rr];
            dgp[bh * SEQ + qbase + i * 16 + rl] = dg;
        }
    }
}

extern "C" void kernel_launch(void* const* d_in, const int* in_sizes, int n_in,
                              void* d_out, int out_size, void* d_ws, size_t ws_size,
                              hipStream_t stream) {
    const float* x  = (const float*)d_in[0];
    const float* Wq = (const float*)d_in[1];
    const float* Wk = (const float*)d_in[2];
    const float* Wv = (const float*)d_in[3];
    float* out = (float*)d_out;
    char* ws = (char*)d_ws;

    const size_t xb_off  = 0;
    const size_t wq_off  = xb_off + (size_t)MROWS * EMB * 2;
    const size_t wk_off  = wq_off + (size_t)NW * 2;          // contiguous after wq
    const size_t wv_off  = wk_off + (size_t)NW * 2;
    const size_t q_off   = wv_off + (size_t)NW * 2;
    const size_t k_off   = q_off + (size_t)MROWS * EMB * 2;  // contiguous after q
    const size_t dg_off  = k_off + (size_t)MROWS * EMB * 2;

    short* xb  = (short*)(ws + xb_off);
    short* wqb = (short*)(ws + wq_off);
    short* wvb = (short*)(ws + wv_off);
    short* Qh  = (short*)(ws + q_off);
    short* Kh  = (short*)(ws + k_off);
    float* dgp = (float*)(ws + dg_off);

    const int npack = (MROWS * EMB + 3 * NW) / 2048;   // 5632 blocks

    pack_all<<<npack, 256, 0, stream>>>(x, Wq, Wk, Wv,
                                        (unsigned short*)xb, (unsigned short*)wqb,
                                        out + (size_t)MROWS * EMB);

    // fused Q+K projection: B = [Wq | Wk] (contiguous), N = 2048
    gemm8<0><<<dim3(MROWS / 256, 2048 / 256), 512, 0, stream>>>(
        xb, wqb, (unsigned short*)Qh, nullptr, nullptr);

    diag_kernel<<<BATCH * HEADS * (SEQ / 256), 512, 0, stream>>>(Qh, Kh, dgp);

    gemm8<1><<<dim3(MROWS / 256, EMB / 128), 512, 0, stream>>>(
        xb, wvb, nullptr, out, dgp);
}